// Round 14
// baseline (251.324 us; speedup 1.0000x reference)
//
#include <hip/hip_runtime.h>
#include <math.h>

#define EMB 128
#define NH 8
#define DH 16
#define HID 256
#define NODE 1000
#define PATCH 196
#define NKEY (NODE + PATCH)   // 1196
#define BB 8
#define POMO 1000
#define KT 16                  // attention key tile
#define RTILES 32              // 32-row tiles
#define TROWS 32

// ---- SCH=7 fallback: partials alias d_out (8M floats) ----
#define SCH7 7
#define CK7 172
#define PACC7_FLOATS 7340032L  // 8*32*7*32*8*16
// ---- SCH=8 fast path: partials live in d_ws ----
#define SCH8 8
#define CK8 152
#define PACC8_FLOATS 8388608L  // 8*32*8*32*8*16
#define PL8_FLOATS   524288L   // 8*32*8*8*32

// ws layout (floats): W5 81920 | Kb 1224704 | Vb 1224704 | Qb 1024000 |
// MH 1024000 | gmid 16 -> base 4579344 (16-aligned) | [pacc8 | pl8]
#define WS_BASE_FLOATS 4579344L
#define WS_NEED_BYTES ((WS_BASE_FLOATS + PACC8_FLOATS + PL8_FLOATS) * 4L)

__device__ __forceinline__ float tanh10(float x) {
    float e = __expf(2.0f * x);
    return 10.0f * (1.0f - 2.0f / (e + 1.0f));
}

// ---------------- hypernet stage 1: pref -> mid[15] -------------------------
__global__ __launch_bounds__(256) void hyper_mid_kernel(
    const float* __restrict__ pref,
    const float* __restrict__ fc1_w, const float* __restrict__ fc1_b,
    const float* __restrict__ fc2_w, const float* __restrict__ fc2_b,
    const float* __restrict__ fc3_w, const float* __restrict__ fc3_b,
    float* __restrict__ gmid)
{
    __shared__ float h1[HID];
    __shared__ float h2[HID];
    int t = threadIdx.x;
    float p0 = pref[0], p1 = pref[1], p2 = pref[2];
    h1[t] = fc1_b[t] + p0 * fc1_w[t * 3 + 0] + p1 * fc1_w[t * 3 + 1] + p2 * fc1_w[t * 3 + 2];
    __syncthreads();
    {
        float s = fc2_b[t];
        const float4* w4 = (const float4*)(fc2_w + t * HID);
        const float4* h4 = (const float4*)h1;
        for (int j = 0; j < HID / 4; ++j) {
            float4 w = w4[j], x = h4[j];
            s += x.x * w.x + x.y * w.y + x.z * w.z + x.w * w.w;
        }
        h2[t] = s;
    }
    __syncthreads();
    if (t < 15) {
        float s = fc3_b[t];
        const float4* w4 = (const float4*)(fc3_w + t * HID);
        const float4* h4 = (const float4*)h2;
        for (int j = 0; j < HID / 4; ++j) {
            float4 w = w4[j], x = h4[j];
            s += x.x * w.x + x.y * w.y + x.z * w.z + x.w * w.w;
        }
        gmid[t] = s;
    }
}

// ---------------- hypernet stage 2: mid -> 5 weight matrices ----------------
__global__ __launch_bounds__(256) void hyper_expand_kernel(
    const float* __restrict__ gmid,
    const float* __restrict__ wqf, const float* __restrict__ wql,
    const float* __restrict__ wk,  const float* __restrict__ wv,
    const float* __restrict__ wc,  float* __restrict__ W5)
{
    int id = blockIdx.x;                 // 40 blocks: 5 mats x 8 segments
    int mat = id >> 3;
    int x0 = (id & 7) * 2048 + threadIdx.x * 8;
    const float* w = (mat == 0) ? wqf : (mat == 1) ? wql : (mat == 2) ? wk : (mat == 3) ? wv : wc;
    float m0 = gmid[mat * 3 + 0], m1 = gmid[mat * 3 + 1], m2 = gmid[mat * 3 + 2];
    float* dst = W5 + mat * EMB * EMB;
    #pragma unroll
    for (int i = 0; i < 8; ++i) {
        int x = x0 + i;
        dst[x] = m0 * w[x * 3 + 0] + m1 * w[x * 3 + 1] + m2 * w[x * 3 + 2];
    }
}

// ---------------- fused K,V + Q projections (one launch) --------------------
__global__ __launch_bounds__(256) void proj_kernel(
    const float* __restrict__ nodes, const float* __restrict__ q1,
    const float* __restrict__ lastn, const float* __restrict__ W5,
    float* __restrict__ Kb, float* __restrict__ Vb, float* __restrict__ Qb)
{
    __shared__ float xa[32][EMB];
    __shared__ float xb[32][EMB];
    int t = threadIdx.x;
    int bid = blockIdx.x;
    if (bid < 299) {
        long r0 = (long)bid * 32;               // over BB*NKEY = 9568
        const float4* s4 = (const float4*)(nodes + r0 * EMB);
        float4* x4p = (float4*)&xa[0][0];
        for (int i = t; i < 32 * EMB / 4; i += 256) x4p[i] = s4[i];
        __syncthreads();
        int o = t;
        const float* W = (o < EMB) ? (W5 + 2 * EMB * EMB + o * EMB)
                                   : (W5 + 3 * EMB * EMB + (o - EMB) * EMB);
        float acc[32];
        #pragma unroll
        for (int r = 0; r < 32; ++r) acc[r] = 0.f;
        for (int e = 0; e < EMB; e += 4) {
            float4 w4 = *(const float4*)&W[e];
            #pragma unroll
            for (int r = 0; r < 32; ++r) {
                float4 x4 = *(const float4*)&xa[r][e];
                acc[r] += x4.x * w4.x + x4.y * w4.y + x4.z * w4.z + x4.w * w4.w;
            }
        }
        float* dst = (o < EMB) ? (Kb + r0 * EMB + o) : (Vb + r0 * EMB + (o - EMB));
        #pragma unroll
        for (int r = 0; r < 32; ++r) dst[(long)r * EMB] = acc[r];
    } else {
        long r0 = (long)(bid - 299) * 32;       // over 8000
        const float4* a4 = (const float4*)(q1 + r0 * EMB);
        const float4* b4 = (const float4*)(lastn + r0 * EMB);
        float4* xap = (float4*)&xa[0][0];
        float4* xbp = (float4*)&xb[0][0];
        for (int i = t; i < 32 * EMB / 4; i += 256) { xap[i] = a4[i]; xbp[i] = b4[i]; }
        __syncthreads();
        int o = t & 127;
        int rbase = (t >> 7) * 16;
        const float* Wf = W5 + 0 * EMB * EMB + o * EMB;
        const float* Wl = W5 + 1 * EMB * EMB + o * EMB;
        float acc[16];
        #pragma unroll
        for (int r = 0; r < 16; ++r) acc[r] = 0.f;
        for (int e = 0; e < EMB; e += 4) {
            float4 wf = *(const float4*)&Wf[e];
            float4 wl = *(const float4*)&Wl[e];
            #pragma unroll
            for (int r = 0; r < 16; ++r) {
                float4 va = *(const float4*)&xa[rbase + r][e];
                float4 vb = *(const float4*)&xb[rbase + r][e];
                acc[r] += va.x * wf.x + va.y * wf.y + va.z * wf.z + va.w * wf.w
                        + vb.x * wl.x + vb.y * wl.y + vb.z * wl.z + vb.w * wl.w;
            }
        }
        #pragma unroll
        for (int r = 0; r < 16; ++r) Qb[(r0 + rbase + r) * EMB + o] = acc[r];
    }
}

// ---------------- fused masked MHA, key-split, NO-max-shift flash -----------
// (verified 128-VGPR kernel, templated on chunk count; setprio inner loop)
// grid (8, 32, SCHT): x=b (XCD-aligned), y=32-row tile, z=key chunk.
template <int SCHT, int CKT>
__global__ __launch_bounds__(128, 2) void attn_split_kernel(
    const float* __restrict__ Kb, const float* __restrict__ Vb,
    const float* __restrict__ Qb, const float* __restrict__ mask,
    float* __restrict__ pacc, float* __restrict__ pl)
{
    __shared__ float ks[KT][EMB];
    __shared__ float vs[KT][EMB];
    int t = threadIdx.x;
    int b = blockIdx.x;
    int tile = blockIdx.y;
    int c = blockIdx.z;
    int rr = t & 15;
    int h = t >> 4;
    int row0 = tile * TROWS + rr * 2;
    bool active = (row0 < POMO);
    int qrow = active ? row0 : (POMO - 2);     // clamped; stores guarded
    int kstart = c * CKT;
    int kend = kstart + CKT; if (kend > NKEY) kend = NKEY;

    float q0[DH], q1r[DH];
    {
        const float4* qp0 = (const float4*)(Qb + ((long)b * POMO + qrow) * EMB + h * DH);
        const float4* qp1 = (const float4*)(Qb + ((long)b * POMO + qrow + 1) * EMB + h * DH);
        #pragma unroll
        for (int i = 0; i < 4; ++i) {
            float4 v = qp0[i];   // pre-scale by 1/sqrt(16): s = q.k + mask
            q0[4*i+0] = v.x*0.25f; q0[4*i+1] = v.y*0.25f;
            q0[4*i+2] = v.z*0.25f; q0[4*i+3] = v.w*0.25f;
            float4 w = qp1[i];
            q1r[4*i+0] = w.x*0.25f; q1r[4*i+1] = w.y*0.25f;
            q1r[4*i+2] = w.z*0.25f; q1r[4*i+3] = w.w*0.25f;
        }
    }
    float acc0[DH], acc1[DH];
    #pragma unroll
    for (int i = 0; i < DH; ++i) { acc0[i] = 0.f; acc1[i] = 0.f; }
    float l0 = 0.f, l1 = 0.f;

    const float4* ksrc = (const float4*)(Kb + (long)b * NKEY * EMB);
    const float4* vsrc = (const float4*)(Vb + (long)b * NKEY * EMB);
    const int max4 = NKEY * (EMB / 4) - 1;
    const float* mrow0 = mask + ((long)b * POMO + qrow) * NODE;
    const float* mrow1 = mrow0 + NODE;

    for (int t0 = kstart; t0 < kend; t0 += KT) {
        int valid = kend - t0; if (valid > KT) valid = KT;
        __syncthreads();
        {   // stage K,V tile via registers (L2-friendly), clamped source
            float4* kd = (float4*)&ks[0][0];
            float4* vd = (float4*)&vs[0][0];
            int base4 = t0 * (EMB / 4);
            #pragma unroll
            for (int u = 0; u < 4; ++u) {
                int i = t + u * 128;
                int src = base4 + i; if (src > max4) src = max4;
                kd[i] = ksrc[src];
                vd[i] = vsrc[src];
            }
        }
        __syncthreads();

        // float4 key-groups carrying mask: j4 < jm (NODE, t0, valid all
        // multiples of 4 -> groups never straddle the node/patch boundary)
        int jm = 0;
        if (t0 < NODE) {
            int lim = NODE - t0; if (lim > valid) lim = valid;
            jm = lim >> 2;
        }
        float mk0[KT], mk1[KT];
        {
            const float4* mp0 = (const float4*)(mrow0 + t0);
            const float4* mp1 = (const float4*)(mrow1 + t0);
            #pragma unroll
            for (int j4 = 0; j4 < KT / 4; ++j4) {
                float4 a = (j4 < jm) ? mp0[j4] : make_float4(0,0,0,0);
                float4 bm = (j4 < jm) ? mp1[j4] : make_float4(0,0,0,0);
                mk0[4*j4+0]=a.x;  mk0[4*j4+1]=a.y;  mk0[4*j4+2]=a.z;  mk0[4*j4+3]=a.w;
                mk1[4*j4+0]=bm.x; mk1[4*j4+1]=bm.y; mk1[4*j4+2]=bm.z; mk1[4*j4+3]=bm.w;
            }
        }

#define INNER(TAIL)                                                          \
        _Pragma("unroll")                                                    \
        for (int j = 0; j < KT; ++j) {                                       \
            float s0 = mk0[j], s1 = mk1[j];                                  \
            _Pragma("unroll")                                                \
            for (int e = 0; e < DH; e += 4) {                                \
                float4 k4 = *(const float4*)&ks[j][h * DH + e];              \
                s0 += q0[e]*k4.x + q0[e+1]*k4.y + q0[e+2]*k4.z + q0[e+3]*k4.w; \
                s1 += q1r[e]*k4.x + q1r[e+1]*k4.y + q1r[e+2]*k4.z + q1r[e+3]*k4.w; \
            }                                                                \
            float p0 = __expf(s0), p1 = __expf(s1);                          \
            if (TAIL && j >= valid) { p0 = 0.f; p1 = 0.f; }                  \
            l0 += p0; l1 += p1;                                              \
            _Pragma("unroll")                                                \
            for (int e = 0; e < DH; e += 4) {                                \
                float4 v4 = *(const float4*)&vs[j][h * DH + e];              \
                acc0[e+0] += p0*v4.x; acc0[e+1] += p0*v4.y;                  \
                acc0[e+2] += p0*v4.z; acc0[e+3] += p0*v4.w;                  \
                acc1[e+0] += p1*v4.x; acc1[e+1] += p1*v4.y;                  \
                acc1[e+2] += p1*v4.z; acc1[e+3] += p1*v4.w;                  \
            }                                                                \
        }
        __builtin_amdgcn_s_setprio(1);
        if (valid == KT) { INNER(false) } else { INNER(true) }
        __builtin_amdgcn_s_setprio(0);
#undef INNER
    }
    if (active) {
        long cb = ((long)(b * RTILES + tile) * SCHT + c);
        long rec0 = ((cb * TROWS + rr * 2) * NH + h) * 16;
        long rec1 = rec0 + (long)NH * 16;
        #pragma unroll
        for (int i = 0; i < 4; ++i) {
            *(float4*)&pacc[rec0 + 4*i] =
                make_float4(acc0[4*i], acc0[4*i+1], acc0[4*i+2], acc0[4*i+3]);
            *(float4*)&pacc[rec1 + 4*i] =
                make_float4(acc1[4*i], acc1[4*i+1], acc1[4*i+2], acc1[4*i+3]);
        }
        long plrec = (cb * NH + h) * TROWS + rr * 2;
        *(float2*)&pl[plrec] = make_float2(l0, l1);
    }
}

// ---------------- fused merge + combine: partials -> MH ---------------------
template <int SCHT>
__global__ __launch_bounds__(256) void merge_combine_kernel(
    const float* __restrict__ pacc, const float* __restrict__ pl,
    const float* __restrict__ W5, float* __restrict__ MH)
{
    __shared__ float xs[32][EMB];
    int t = threadIdx.x;
    int b = blockIdx.x, tile = blockIdx.y;
    {   // phase 1: merge
        int rt = t >> 3, h = t & 7;
        int row = tile * TROWS + rt;
        float o[16];
        #pragma unroll
        for (int i = 0; i < 16; ++i) o[i] = 0.f;
        if (row < POMO) {
            long cb0 = (long)(b * RTILES + tile) * SCHT;
            const long cs_acc = (long)TROWS * NH * 16;   // 4096 floats/chunk
            long abase = cb0 * cs_acc + ((long)rt * NH + h) * 16;
            const long cs_pl = (long)NH * TROWS;         // 256 floats/chunk
            long lbase = cb0 * cs_pl + (long)h * TROWS + rt;
            float L = 0.f;
            #pragma unroll
            for (int c = 0; c < SCHT; ++c) {
                L += pl[lbase + c * cs_pl];
                #pragma unroll
                for (int i4 = 0; i4 < 4; ++i4) {
                    float4 a = *(const float4*)&pacc[abase + c * cs_acc + 4 * i4];
                    o[4*i4+0] += a.x; o[4*i4+1] += a.y;
                    o[4*i4+2] += a.z; o[4*i4+3] += a.w;
                }
            }
            float inv = 1.0f / L;
            #pragma unroll
            for (int i = 0; i < 16; ++i) o[i] *= inv;
        }
        float* xp = &xs[rt][h * DH];
        #pragma unroll
        for (int i4 = 0; i4 < 4; ++i4)
            *(float4*)&xp[4*i4] = make_float4(o[4*i4], o[4*i4+1], o[4*i4+2], o[4*i4+3]);
    }
    __syncthreads();
    {   // phase 2: combine (mh = oc @ Wc.T)
        int o = t & 127;
        int rbase = (t >> 7) * 16;
        const float* W = W5 + 4 * EMB * EMB + o * EMB;
        float acc[16];
        #pragma unroll
        for (int r = 0; r < 16; ++r) acc[r] = 0.f;
        for (int e = 0; e < EMB; e += 4) {
            float4 w4 = *(const float4*)&W[e];
            #pragma unroll
            for (int r = 0; r < 16; ++r) {
                float4 x4 = *(const float4*)&xs[rbase + r][e];
                acc[r] += x4.x * w4.x + x4.y * w4.y + x4.z * w4.z + x4.w * w4.w;
            }
        }
        long row0 = (long)tile * TROWS + rbase;
        #pragma unroll
        for (int r = 0; r < 16; ++r) {
            long row = row0 + r;
            if (row < POMO)
                MH[((long)b * POMO + row) * EMB + o] = acc[r];
        }
    }
}

// ---------------- logits: exp(10*tanh((mh@nodes.T)/sqrt128) + mask) ---------
__global__ __launch_bounds__(256, 2) void logits_kernel(
    const float* __restrict__ MH, const float* __restrict__ nodes,
    const float* __restrict__ mask, float* __restrict__ out)
{
    __shared__ float As[32][64];    // [e][n] 8 KB
    __shared__ float Bs[32][192];   // [e][16 groups * 12] 24 KB
    int t = threadIdx.x;
    int b = blockIdx.x;
    int n0 = blockIdx.y * 64;       // pomo rows
    int m0 = blockIdx.z * 128;      // node cols
    int ci = t & 15, ri = t >> 4;

    float acc[4][8];
    #pragma unroll
    for (int i = 0; i < 4; ++i)
        #pragma unroll
        for (int j = 0; j < 8; ++j) acc[i][j] = 0.f;

    int lnA = t & 63;
    int ehA = (t >> 6) * 8;
    int arow = n0 + lnA; if (arow >= POMO) arow = POMO - 1;   // clamp reads
    const float* Arow = MH + ((long)b * POMO + arow) * EMB;
    int lnB = t & 127;
    int ehB = (t >> 7) * 16;
    const float* Brow = nodes + ((long)b * NKEY + m0 + lnB) * EMB;  // m0+127<NKEY
    int bcol = (lnB >> 3) * 12 + (lnB & 7);

    for (int e0 = 0; e0 < EMB; e0 += 32) {
        if (e0) __syncthreads();
        #pragma unroll
        for (int u = 0; u < 2; ++u) {
            int e = ehA + u * 4;
            float4 a4 = *(const float4*)&Arow[e0 + e];
            As[e + 0][lnA] = a4.x; As[e + 1][lnA] = a4.y;
            As[e + 2][lnA] = a4.z; As[e + 3][lnA] = a4.w;
        }
        #pragma unroll
        for (int u = 0; u < 4; ++u) {
            int e = ehB + u * 4;
            float4 b4 = *(const float4*)&Brow[e0 + e];
            Bs[e + 0][bcol] = b4.x; Bs[e + 1][bcol] = b4.y;
            Bs[e + 2][bcol] = b4.z; Bs[e + 3][bcol] = b4.w;
        }
        __syncthreads();
        #pragma unroll
        for (int e = 0; e < 32; ++e) {
            float4 a0 = *(const float4*)&As[e][ri * 4];
            float4 b0 = *(const float4*)&Bs[e][ci * 12];
            float4 b1 = *(const float4*)&Bs[e][ci * 12 + 4];
            float av[4] = {a0.x, a0.y, a0.z, a0.w};
            float bv[8] = {b0.x, b0.y, b0.z, b0.w, b1.x, b1.y, b1.z, b1.w};
            #pragma unroll
            for (int i = 0; i < 4; ++i)
                #pragma unroll
                for (int j = 0; j < 8; ++j)
                    acc[i][j] += av[i] * bv[j];
        }
    }
    const float inv = 0.08838834764831845f;  // 1/sqrt(128)
    bool mfull = (m0 + 127 < NODE);
    int m = m0 + ci * 8;
    #pragma unroll
    for (int i = 0; i < 4; ++i) {
        int n = n0 + ri * 4 + i;
        if (n >= POMO) continue;
        long rbase = ((long)b * POMO + n) * NODE;
        if (mfull) {
            #pragma unroll
            for (int j4 = 0; j4 < 2; ++j4) {
                float4 mk = *(const float4*)&mask[rbase + m + j4 * 4];
                float4 r;
                r.x = __expf(tanh10(acc[i][j4*4+0] * inv) + mk.x);
                r.y = __expf(tanh10(acc[i][j4*4+1] * inv) + mk.y);
                r.z = __expf(tanh10(acc[i][j4*4+2] * inv) + mk.z);
                r.w = __expf(tanh10(acc[i][j4*4+3] * inv) + mk.w);
                *(float4*)&out[rbase + m + j4 * 4] = r;
            }
        } else {
            #pragma unroll
            for (int j = 0; j < 8; ++j) {
                int mm = m + j;
                if (mm < NODE)
                    out[rbase + mm] = __expf(tanh10(acc[i][j] * inv) + mask[rbase + mm]);
            }
        }
    }
}

// ---------------- normalize: divide row by its sum (exp already applied) ----
__global__ __launch_bounds__(256) void normalize_kernel(float* __restrict__ out)
{
    __shared__ float wred[4];
    int t = threadIdx.x;
    int w = t >> 6;
    float* p = out + (long)blockIdx.x * NODE;
    bool act = t < 250;
    float4 x = act ? *(const float4*)&p[t * 4] : make_float4(0.f, 0.f, 0.f, 0.f);
    float sm = x.x + x.y + x.z + x.w;
    #pragma unroll
    for (int s = 32; s >= 1; s >>= 1) sm += __shfl_xor(sm, s);
    if ((t & 63) == 0) wred[w] = sm;
    __syncthreads();
    float inv = 1.0f / (wred[0] + wred[1] + wred[2] + wred[3]);
    if (act) {
        float4 rr;
        rr.x = x.x * inv; rr.y = x.y * inv; rr.z = x.z * inv; rr.w = x.w * inv;
        *(float4*)&p[t * 4] = rr;
    }
}

extern "C" void kernel_launch(void* const* d_in, const int* in_sizes, int n_in,
                              void* d_out, int out_size, void* d_ws, size_t ws_size,
                              hipStream_t stream)
{
    const float* pref  = (const float*)d_in[0];
    const float* nodes = (const float*)d_in[1];
    const float* q1    = (const float*)d_in[2];
    const float* lastn = (const float*)d_in[3];
    const float* mask  = (const float*)d_in[4];
    const float* fc1_w = (const float*)d_in[5];
    const float* fc1_b = (const float*)d_in[6];
    const float* fc2_w = (const float*)d_in[7];
    const float* fc2_b = (const float*)d_in[8];
    const float* fc3_w = (const float*)d_in[9];
    const float* fc3_b = (const float*)d_in[10];
    const float* wqf   = (const float*)d_in[11];
    const float* wql   = (const float*)d_in[12];
    const float* wk    = (const float*)d_in[13];
    const float* wv    = (const float*)d_in[14];
    const float* wc    = (const float*)d_in[15];
    float* out = (float*)d_out;
    float* ws  = (float*)d_ws;

    float* W5 = ws;                                   // 5*16384 = 81920
    float* Kb = ws + 81920;                           // 8*1196*128
    float* Vb = Kb + (long)BB * NKEY * EMB;
    float* Qb = Vb + (long)BB * NKEY * EMB;           // 8*1000*128
    float* MH = Qb + (long)BB * POMO * EMB;
    float* gmid = MH + (long)BB * POMO * EMB;         // base 4,579,344 floats

    bool big_ws = (ws_size >= (size_t)WS_NEED_BYTES);

    hipLaunchKernelGGL(hyper_mid_kernel, dim3(1), dim3(256), 0, stream,
                       pref, fc1_w, fc1_b, fc2_w, fc2_b, fc3_w, fc3_b, gmid);
    hipLaunchKernelGGL(hyper_expand_kernel, dim3(40), dim3(256), 0, stream,
                       gmid, wqf, wql, wk, wv, wc, W5);
    hipLaunchKernelGGL(proj_kernel, dim3(549), dim3(256), 0, stream,
                       nodes, q1, lastn, W5, Kb, Vb, Qb);
    if (big_ws) {
        // SCH=8: 2048 blocks = exactly 8 blocks/CU; partials in ws
        float* pacc = ws + WS_BASE_FLOATS;
        float* pl   = pacc + PACC8_FLOATS;
        hipLaunchKernelGGL((attn_split_kernel<SCH8, CK8>), dim3(8, RTILES, SCH8),
                           dim3(128), 0, stream, Kb, Vb, Qb, mask, pacc, pl);
        hipLaunchKernelGGL((merge_combine_kernel<SCH8>), dim3(8, RTILES),
                           dim3(256), 0, stream, pacc, pl, W5, MH);
    } else {
        // SCH=7 fallback: partials alias d_out (overwritten by logits later)
        float* pacc = out;
        float* pl   = out + PACC7_FLOATS;
        hipLaunchKernelGGL((attn_split_kernel<SCH7, CK7>), dim3(8, RTILES, SCH7),
                           dim3(128), 0, stream, Kb, Vb, Qb, mask, pacc, pl);
        hipLaunchKernelGGL((merge_combine_kernel<SCH7>), dim3(8, RTILES),
                           dim3(256), 0, stream, pacc, pl, W5, MH);
    }
    hipLaunchKernelGGL(logits_kernel, dim3(8, 16, 8), dim3(256), 0, stream,
                       MH, nodes, mask, out);
    hipLaunchKernelGGL(normalize_kernel, dim3(8000), dim3(256), 0, stream, out);
}

// Round 15
// 244.477 us; speedup vs baseline: 1.0280x; 1.0280x over previous
//
#include <hip/hip_runtime.h>
#include <math.h>

#define EMB 128
#define NH 8
#define DH 16
#define HID 256
#define NODE 1000
#define PATCH 196
#define NKEY (NODE + PATCH)   // 1196
#define BB 8
#define POMO 1000
#define KT 16                  // attention key tile
#define SCH 7                  // key-split chunks
#define CKEYS 172              // keys per chunk (last = 164)
#define RTILES 32              // 32-row tiles
#define TROWS 32

// partial buffers alias d_out (8M floats):
// pacc: [b][tile][chunk][row32][h][16] = 8*32*7*32*8*16 = 7,340,032 floats
// pl  : [b][tile][chunk][h][row32]     = 8*32*7*8*32    =   458,752 floats
#define PACC_FLOATS 7340032L

__device__ __forceinline__ float tanh10(float x) {
    float e = __expf(2.0f * x);
    return 10.0f * (1.0f - 2.0f / (e + 1.0f));
}

// ---------------- hypernet stage 1: pref -> mid[15] -------------------------
__global__ __launch_bounds__(256) void hyper_mid_kernel(
    const float* __restrict__ pref,
    const float* __restrict__ fc1_w, const float* __restrict__ fc1_b,
    const float* __restrict__ fc2_w, const float* __restrict__ fc2_b,
    const float* __restrict__ fc3_w, const float* __restrict__ fc3_b,
    float* __restrict__ gmid)
{
    __shared__ float h1[HID];
    __shared__ float h2[HID];
    int t = threadIdx.x;
    float p0 = pref[0], p1 = pref[1], p2 = pref[2];
    h1[t] = fc1_b[t] + p0 * fc1_w[t * 3 + 0] + p1 * fc1_w[t * 3 + 1] + p2 * fc1_w[t * 3 + 2];
    __syncthreads();
    {
        float s = fc2_b[t];
        const float4* w4 = (const float4*)(fc2_w + t * HID);
        const float4* h4 = (const float4*)h1;
        for (int j = 0; j < HID / 4; ++j) {
            float4 w = w4[j], x = h4[j];
            s += x.x * w.x + x.y * w.y + x.z * w.z + x.w * w.w;
        }
        h2[t] = s;
    }
    __syncthreads();
    if (t < 15) {
        float s = fc3_b[t];
        const float4* w4 = (const float4*)(fc3_w + t * HID);
        const float4* h4 = (const float4*)h2;
        for (int j = 0; j < HID / 4; ++j) {
            float4 w = w4[j], x = h4[j];
            s += x.x * w.x + x.y * w.y + x.z * w.z + x.w * w.w;
        }
        gmid[t] = s;
    }
}

// ---------------- hypernet stage 2: mid -> 5 weight matrices ----------------
__global__ __launch_bounds__(256) void hyper_expand_kernel(
    const float* __restrict__ gmid,
    const float* __restrict__ wqf, const float* __restrict__ wql,
    const float* __restrict__ wk,  const float* __restrict__ wv,
    const float* __restrict__ wc,  float* __restrict__ W5)
{
    int id = blockIdx.x;                 // 40 blocks: 5 mats x 8 segments
    int mat = id >> 3;
    int x0 = (id & 7) * 2048 + threadIdx.x * 8;
    const float* w = (mat == 0) ? wqf : (mat == 1) ? wql : (mat == 2) ? wk : (mat == 3) ? wv : wc;
    float m0 = gmid[mat * 3 + 0], m1 = gmid[mat * 3 + 1], m2 = gmid[mat * 3 + 2];
    float* dst = W5 + mat * EMB * EMB;
    #pragma unroll
    for (int i = 0; i < 8; ++i) {
        int x = x0 + i;
        dst[x] = m0 * w[x * 3 + 0] + m1 * w[x * 3 + 1] + m2 * w[x * 3 + 2];
    }
}

// ---------------- fused K,V + Q projections (one launch) --------------------
__global__ __launch_bounds__(256) void proj_kernel(
    const float* __restrict__ nodes, const float* __restrict__ q1,
    const float* __restrict__ lastn, const float* __restrict__ W5,
    float* __restrict__ Kb, float* __restrict__ Vb, float* __restrict__ Qb)
{
    __shared__ float xa[32][EMB];
    __shared__ float xb[32][EMB];
    int t = threadIdx.x;
    int bid = blockIdx.x;
    if (bid < 299) {
        // ---- K/V path ----
        long r0 = (long)bid * 32;               // over BB*NKEY = 9568
        const float4* s4 = (const float4*)(nodes + r0 * EMB);
        float4* x4p = (float4*)&xa[0][0];
        for (int i = t; i < 32 * EMB / 4; i += 256) x4p[i] = s4[i];
        __syncthreads();
        int o = t;
        const float* W = (o < EMB) ? (W5 + 2 * EMB * EMB + o * EMB)
                                   : (W5 + 3 * EMB * EMB + (o - EMB) * EMB);
        float acc[32];
        #pragma unroll
        for (int r = 0; r < 32; ++r) acc[r] = 0.f;
        for (int e = 0; e < EMB; e += 4) {
            float4 w4 = *(const float4*)&W[e];
            #pragma unroll
            for (int r = 0; r < 32; ++r) {
                float4 x4 = *(const float4*)&xa[r][e];
                acc[r] += x4.x * w4.x + x4.y * w4.y + x4.z * w4.z + x4.w * w4.w;
            }
        }
        float* dst = (o < EMB) ? (Kb + r0 * EMB + o) : (Vb + r0 * EMB + (o - EMB));
        #pragma unroll
        for (int r = 0; r < 32; ++r) dst[(long)r * EMB] = acc[r];
    } else {
        // ---- Q path: q1@Wqf.T + last@Wql.T ----
        long r0 = (long)(bid - 299) * 32;       // over 8000
        const float4* a4 = (const float4*)(q1 + r0 * EMB);
        const float4* b4 = (const float4*)(lastn + r0 * EMB);
        float4* xap = (float4*)&xa[0][0];
        float4* xbp = (float4*)&xb[0][0];
        for (int i = t; i < 32 * EMB / 4; i += 256) { xap[i] = a4[i]; xbp[i] = b4[i]; }
        __syncthreads();
        int o = t & 127;
        int rbase = (t >> 7) * 16;
        const float* Wf = W5 + 0 * EMB * EMB + o * EMB;
        const float* Wl = W5 + 1 * EMB * EMB + o * EMB;
        float acc[16];
        #pragma unroll
        for (int r = 0; r < 16; ++r) acc[r] = 0.f;
        for (int e = 0; e < EMB; e += 4) {
            float4 wf = *(const float4*)&Wf[e];
            float4 wl = *(const float4*)&Wl[e];
            #pragma unroll
            for (int r = 0; r < 16; ++r) {
                float4 va = *(const float4*)&xa[rbase + r][e];
                float4 vb = *(const float4*)&xb[rbase + r][e];
                acc[r] += va.x * wf.x + va.y * wf.y + va.z * wf.z + va.w * wf.w
                        + vb.x * wl.x + vb.y * wl.y + vb.z * wl.z + vb.w * wl.w;
            }
        }
        #pragma unroll
        for (int r = 0; r < 16; ++r) Qb[(r0 + rbase + r) * EMB + o] = acc[r];
    }
}

// ---------------- fused masked MHA, key-split, NO-max-shift flash -----------
// (verified 128-VGPR kernel; + s_setprio around the inner loop (T5))
// grid (8, 32, 7): x=b (XCD-aligned), y=32-row tile, z=key chunk.
__global__ __launch_bounds__(128, 2) void attn_split_kernel(
    const float* __restrict__ Kb, const float* __restrict__ Vb,
    const float* __restrict__ Qb, const float* __restrict__ mask,
    float* __restrict__ pacc, float* __restrict__ pl)
{
    __shared__ float ks[KT][EMB];
    __shared__ float vs[KT][EMB];
    int t = threadIdx.x;
    int b = blockIdx.x;
    int tile = blockIdx.y;
    int c = blockIdx.z;
    int rr = t & 15;
    int h = t >> 4;
    int row0 = tile * TROWS + rr * 2;
    bool active = (row0 < POMO);
    int qrow = active ? row0 : (POMO - 2);     // clamped; stores guarded
    int kstart = c * CKEYS;
    int kend = kstart + CKEYS; if (kend > NKEY) kend = NKEY;

    float q0[DH], q1r[DH];
    {
        const float4* qp0 = (const float4*)(Qb + ((long)b * POMO + qrow) * EMB + h * DH);
        const float4* qp1 = (const float4*)(Qb + ((long)b * POMO + qrow + 1) * EMB + h * DH);
        #pragma unroll
        for (int i = 0; i < 4; ++i) {
            float4 v = qp0[i];   // pre-scale by 1/sqrt(16): s = q.k + mask
            q0[4*i+0] = v.x*0.25f; q0[4*i+1] = v.y*0.25f;
            q0[4*i+2] = v.z*0.25f; q0[4*i+3] = v.w*0.25f;
            float4 w = qp1[i];
            q1r[4*i+0] = w.x*0.25f; q1r[4*i+1] = w.y*0.25f;
            q1r[4*i+2] = w.z*0.25f; q1r[4*i+3] = w.w*0.25f;
        }
    }
    float acc0[DH], acc1[DH];
    #pragma unroll
    for (int i = 0; i < DH; ++i) { acc0[i] = 0.f; acc1[i] = 0.f; }
    float l0 = 0.f, l1 = 0.f;

    const float4* ksrc = (const float4*)(Kb + (long)b * NKEY * EMB);
    const float4* vsrc = (const float4*)(Vb + (long)b * NKEY * EMB);
    const int max4 = NKEY * (EMB / 4) - 1;
    const float* mrow0 = mask + ((long)b * POMO + qrow) * NODE;
    const float* mrow1 = mrow0 + NODE;

    for (int t0 = kstart; t0 < kend; t0 += KT) {
        int valid = kend - t0; if (valid > KT) valid = KT;   // 16, 12 or 4
        __syncthreads();
        {   // stage K,V tile via registers (L2-friendly), clamped source
            float4* kd = (float4*)&ks[0][0];
            float4* vd = (float4*)&vs[0][0];
            int base4 = t0 * (EMB / 4);
            #pragma unroll
            for (int u = 0; u < 4; ++u) {
                int i = t + u * 128;
                int src = base4 + i; if (src > max4) src = max4;
                kd[i] = ksrc[src];
                vd[i] = vsrc[src];
            }
        }
        __syncthreads();

        // float4 key-groups carrying mask: j4 < jm (NODE, t0, valid all
        // multiples of 4 -> groups never straddle the node/patch boundary)
        int jm = 0;
        if (t0 < NODE) {
            int lim = NODE - t0; if (lim > valid) lim = valid;
            jm = lim >> 2;
        }
        float mk0[KT], mk1[KT];
        {
            const float4* mp0 = (const float4*)(mrow0 + t0);
            const float4* mp1 = (const float4*)(mrow1 + t0);
            #pragma unroll
            for (int j4 = 0; j4 < KT / 4; ++j4) {
                float4 a = (j4 < jm) ? mp0[j4] : make_float4(0,0,0,0);
                float4 bm = (j4 < jm) ? mp1[j4] : make_float4(0,0,0,0);
                mk0[4*j4+0]=a.x;  mk0[4*j4+1]=a.y;  mk0[4*j4+2]=a.z;  mk0[4*j4+3]=a.w;
                mk1[4*j4+0]=bm.x; mk1[4*j4+1]=bm.y; mk1[4*j4+2]=bm.z; mk1[4*j4+3]=bm.w;
            }
        }

#define INNER(TAIL)                                                          \
        _Pragma("unroll")                                                    \
        for (int j = 0; j < KT; ++j) {                                       \
            float s0 = mk0[j], s1 = mk1[j];                                  \
            _Pragma("unroll")                                                \
            for (int e = 0; e < DH; e += 4) {                                \
                float4 k4 = *(const float4*)&ks[j][h * DH + e];              \
                s0 += q0[e]*k4.x + q0[e+1]*k4.y + q0[e+2]*k4.z + q0[e+3]*k4.w; \
                s1 += q1r[e]*k4.x + q1r[e+1]*k4.y + q1r[e+2]*k4.z + q1r[e+3]*k4.w; \
            }                                                                \
            float p0 = __expf(s0), p1 = __expf(s1);                          \
            if (TAIL && j >= valid) { p0 = 0.f; p1 = 0.f; }                  \
            l0 += p0; l1 += p1;                                              \
            _Pragma("unroll")                                                \
            for (int e = 0; e < DH; e += 4) {                                \
                float4 v4 = *(const float4*)&vs[j][h * DH + e];              \
                acc0[e+0] += p0*v4.x; acc0[e+1] += p0*v4.y;                  \
                acc0[e+2] += p0*v4.z; acc0[e+3] += p0*v4.w;                  \
                acc1[e+0] += p1*v4.x; acc1[e+1] += p1*v4.y;                  \
                acc1[e+2] += p1*v4.z; acc1[e+3] += p1*v4.w;                  \
            }                                                                \
        }
        __builtin_amdgcn_s_setprio(1);
        if (valid == KT) { INNER(false) } else { INNER(true) }
        __builtin_amdgcn_s_setprio(0);
#undef INNER
    }
    if (active) {
        long cb = ((long)(b * RTILES + tile) * SCH + c);
        // pacc: [cb][row32][h][16] -- dense 64B records, full-line wave stores
        long rec0 = ((cb * TROWS + rr * 2) * NH + h) * 16;
        long rec1 = rec0 + (long)NH * 16;
        #pragma unroll
        for (int i = 0; i < 4; ++i) {
            *(float4*)&pacc[rec0 + 4*i] =
                make_float4(acc0[4*i], acc0[4*i+1], acc0[4*i+2], acc0[4*i+3]);
            *(float4*)&pacc[rec1 + 4*i] =
                make_float4(acc1[4*i], acc1[4*i+1], acc1[4*i+2], acc1[4*i+3]);
        }
        // pl: [cb][h][row32] -- contiguous per (cb,h)
        long plrec = (cb * NH + h) * TROWS + rr * 2;
        *(float2*)&pl[plrec] = make_float2(l0, l1);
    }
}

// ---------------- fused merge + combine: partials -> MH ---------------------
__global__ __launch_bounds__(256) void merge_combine_kernel(
    const float* __restrict__ pacc, const float* __restrict__ pl,
    const float* __restrict__ W5, float* __restrict__ MH)
{
    __shared__ float xs[32][EMB];
    int t = threadIdx.x;
    int b = blockIdx.x, tile = blockIdx.y;
    {   // phase 1: merge
        int rt = t >> 3, h = t & 7;
        int row = tile * TROWS + rt;
        float o[16];
        #pragma unroll
        for (int i = 0; i < 16; ++i) o[i] = 0.f;
        if (row < POMO) {
            long cb0 = (long)(b * RTILES + tile) * SCH;
            const long cs_acc = (long)TROWS * NH * 16;   // 4096 floats/chunk
            long abase = cb0 * cs_acc + ((long)rt * NH + h) * 16;
            const long cs_pl = (long)NH * TROWS;         // 256 floats/chunk
            long lbase = cb0 * cs_pl + (long)h * TROWS + rt;
            float L = 0.f;
            #pragma unroll
            for (int c = 0; c < SCH; ++c) {
                L += pl[lbase + c * cs_pl];
                #pragma unroll
                for (int i4 = 0; i4 < 4; ++i4) {
                    float4 a = *(const float4*)&pacc[abase + c * cs_acc + 4 * i4];
                    o[4*i4+0] += a.x; o[4*i4+1] += a.y;
                    o[4*i4+2] += a.z; o[4*i4+3] += a.w;
                }
            }
            float inv = 1.0f / L;
            #pragma unroll
            for (int i = 0; i < 16; ++i) o[i] *= inv;
        }
        float* xp = &xs[rt][h * DH];
        #pragma unroll
        for (int i4 = 0; i4 < 4; ++i4)
            *(float4*)&xp[4*i4] = make_float4(o[4*i4], o[4*i4+1], o[4*i4+2], o[4*i4+3]);
    }
    __syncthreads();
    {   // phase 2: combine (mh = oc @ Wc.T)
        int o = t & 127;
        int rbase = (t >> 7) * 16;
        const float* W = W5 + 4 * EMB * EMB + o * EMB;
        float acc[16];
        #pragma unroll
        for (int r = 0; r < 16; ++r) acc[r] = 0.f;
        for (int e = 0; e < EMB; e += 4) {
            float4 w4 = *(const float4*)&W[e];
            #pragma unroll
            for (int r = 0; r < 16; ++r) {
                float4 x4 = *(const float4*)&xs[rbase + r][e];
                acc[r] += x4.x * w4.x + x4.y * w4.y + x4.z * w4.z + x4.w * w4.w;
            }
        }
        long row0 = (long)tile * TROWS + rbase;
        #pragma unroll
        for (int r = 0; r < 16; ++r) {
            long row = row0 + r;
            if (row < POMO)
                MH[((long)b * POMO + row) * EMB + o] = acc[r];
        }
    }
}

// ---------------- logits: exp(10*tanh((mh@nodes.T)/sqrt128) + mask) ---------
// 64x128 tile (grid (8,16,8) = 1024 blocks = 4/CU), 4x8 register tile.
// Writes UNNORMALIZED softmax numerators; normalize_kernel divides by sum.
__global__ __launch_bounds__(256, 2) void logits_kernel(
    const float* __restrict__ MH, const float* __restrict__ nodes,
    const float* __restrict__ mask, float* __restrict__ out)
{
    __shared__ float As[32][64];    // [e][n] 8 KB
    __shared__ float Bs[32][192];   // [e][16 groups * 12] 24 KB
    int t = threadIdx.x;
    int b = blockIdx.x;
    int n0 = blockIdx.y * 64;       // pomo rows
    int m0 = blockIdx.z * 128;      // node cols
    int ci = t & 15, ri = t >> 4;

    float acc[4][8];
    #pragma unroll
    for (int i = 0; i < 4; ++i)
        #pragma unroll
        for (int j = 0; j < 8; ++j) acc[i][j] = 0.f;

    int lnA = t & 63;
    int ehA = (t >> 6) * 8;
    int arow = n0 + lnA; if (arow >= POMO) arow = POMO - 1;   // clamp reads
    const float* Arow = MH + ((long)b * POMO + arow) * EMB;
    int lnB = t & 127;
    int ehB = (t >> 7) * 16;
    const float* Brow = nodes + ((long)b * NKEY + m0 + lnB) * EMB;  // m0+127<NKEY
    int bcol = (lnB >> 3) * 12 + (lnB & 7);

    for (int e0 = 0; e0 < EMB; e0 += 32) {
        if (e0) __syncthreads();
        #pragma unroll
        for (int u = 0; u < 2; ++u) {
            int e = ehA + u * 4;
            float4 a4 = *(const float4*)&Arow[e0 + e];
            As[e + 0][lnA] = a4.x; As[e + 1][lnA] = a4.y;
            As[e + 2][lnA] = a4.z; As[e + 3][lnA] = a4.w;
        }
        #pragma unroll
        for (int u = 0; u < 4; ++u) {
            int e = ehB + u * 4;
            float4 b4 = *(const float4*)&Brow[e0 + e];
            Bs[e + 0][bcol] = b4.x; Bs[e + 1][bcol] = b4.y;
            Bs[e + 2][bcol] = b4.z; Bs[e + 3][bcol] = b4.w;
        }
        __syncthreads();
        #pragma unroll
        for (int e = 0; e < 32; ++e) {
            float4 a0 = *(const float4*)&As[e][ri * 4];
            float4 b0 = *(const float4*)&Bs[e][ci * 12];
            float4 b1 = *(const float4*)&Bs[e][ci * 12 + 4];
            float av[4] = {a0.x, a0.y, a0.z, a0.w};
            float bv[8] = {b0.x, b0.y, b0.z, b0.w, b1.x, b1.y, b1.z, b1.w};
            #pragma unroll
            for (int i = 0; i < 4; ++i)
                #pragma unroll
                for (int j = 0; j < 8; ++j)
                    acc[i][j] += av[i] * bv[j];
        }
    }
    const float inv = 0.08838834764831845f;  // 1/sqrt(128)
    bool mfull = (m0 + 127 < NODE);
    int m = m0 + ci * 8;
    #pragma unroll
    for (int i = 0; i < 4; ++i) {
        int n = n0 + ri * 4 + i;
        if (n >= POMO) continue;
        long rbase = ((long)b * POMO + n) * NODE;
        if (mfull) {
            #pragma unroll
            for (int j4 = 0; j4 < 2; ++j4) {
                float4 mk = *(const float4*)&mask[rbase + m + j4 * 4];
                float4 r;
                r.x = __expf(tanh10(acc[i][j4*4+0] * inv) + mk.x);
                r.y = __expf(tanh10(acc[i][j4*4+1] * inv) + mk.y);
                r.z = __expf(tanh10(acc[i][j4*4+2] * inv) + mk.z);
                r.w = __expf(tanh10(acc[i][j4*4+3] * inv) + mk.w);
                *(float4*)&out[rbase + m + j4 * 4] = r;
            }
        } else {
            #pragma unroll
            for (int j = 0; j < 8; ++j) {
                int mm = m + j;
                if (mm < NODE)
                    out[rbase + mm] = __expf(tanh10(acc[i][j] * inv) + mask[rbase + mm]);
            }
        }
    }
}

// ---------------- normalize: divide row by its sum (exp already applied) ----
__global__ __launch_bounds__(256) void normalize_kernel(float* __restrict__ out)
{
    __shared__ float wred[4];
    int t = threadIdx.x;
    int w = t >> 6;
    float* p = out + (long)blockIdx.x * NODE;
    bool act = t < 250;
    float4 x = act ? *(const float4*)&p[t * 4] : make_float4(0.f, 0.f, 0.f, 0.f);
    float sm = x.x + x.y + x.z + x.w;
    #pragma unroll
    for (int s = 32; s >= 1; s >>= 1) sm += __shfl_xor(sm, s);
    if ((t & 63) == 0) wred[w] = sm;
    __syncthreads();
    float inv = 1.0f / (wred[0] + wred[1] + wred[2] + wred[3]);
    if (act) {
        float4 rr;
        rr.x = x.x * inv; rr.y = x.y * inv; rr.z = x.z * inv; rr.w = x.w * inv;
        *(float4*)&p[t * 4] = rr;
    }
}

extern "C" void kernel_launch(void* const* d_in, const int* in_sizes, int n_in,
                              void* d_out, int out_size, void* d_ws, size_t ws_size,
                              hipStream_t stream)
{
    const float* pref  = (const float*)d_in[0];
    const float* nodes = (const float*)d_in[1];
    const float* q1    = (const float*)d_in[2];
    const float* lastn = (const float*)d_in[3];
    const float* mask  = (const float*)d_in[4];
    const float* fc1_w = (const float*)d_in[5];
    const float* fc1_b = (const float*)d_in[6];
    const float* fc2_w = (const float*)d_in[7];
    const float* fc2_b = (const float*)d_in[8];
    const float* fc3_w = (const float*)d_in[9];
    const float* fc3_b = (const float*)d_in[10];
    const float* wqf   = (const float*)d_in[11];
    const float* wql   = (const float*)d_in[12];
    const float* wk    = (const float*)d_in[13];
    const float* wv    = (const float*)d_in[14];
    const float* wc    = (const float*)d_in[15];
    float* out = (float*)d_out;
    float* ws  = (float*)d_ws;

    float* W5 = ws;                                   // 5*16384 = 81920
    float* Kb = ws + 81920;                           // 8*1196*128
    float* Vb = Kb + (long)BB * NKEY * EMB;
    float* Qb = Vb + (long)BB * NKEY * EMB;           // 8*1000*128
    float* MH = Qb + (long)BB * POMO * EMB;
    float* gmid = MH + (long)BB * POMO * EMB;         // 16 floats, ~18.3 MB total

    float* pacc = out;                 // d_out (8M floats) as partial scratch
    float* pl   = out + PACC_FLOATS;   // 7.34M + 0.46M = 7.8M <= 8M; fully
                                       // overwritten by logits afterwards

    hipLaunchKernelGGL(hyper_mid_kernel, dim3(1), dim3(256), 0, stream,
                       pref, fc1_w, fc1_b, fc2_w, fc2_b, fc3_w, fc3_b, gmid);
    hipLaunchKernelGGL(hyper_expand_kernel, dim3(40), dim3(256), 0, stream,
                       gmid, wqf, wql, wk, wv, wc, W5);
    hipLaunchKernelGGL(proj_kernel, dim3(549), dim3(256), 0, stream,
                       nodes, q1, lastn, W5, Kb, Vb, Qb);
    hipLaunchKernelGGL(attn_split_kernel, dim3(8, RTILES, SCH), dim3(128), 0, stream,
                       Kb, Vb, Qb, mask, pacc, pl);
    hipLaunchKernelGGL(merge_combine_kernel, dim3(8, RTILES), dim3(256), 0, stream,
                       pacc, pl, W5, MH);
    hipLaunchKernelGGL(logits_kernel, dim3(8, 16, 8), dim3(256), 0, stream,
                       MH, nodes, mask, out);
    hipLaunchKernelGGL(normalize_kernel, dim3(8000), dim3(256), 0, stream, out);
}